// Round 8
// baseline (150.280 us; speedup 1.0000x reference)
//
#include <hip/hip_runtime.h>

// Problem constants
#define NROWS 8192   // 4 * 2048
#define DIM   512
#define NTB   32                    // 8192 / 256 tiles per side
#define NTRI  (NTB * (NTB + 1) / 2) // 528 upper-triangular 256x256 tiles
#define NGRID 256                   // persistent blocks (1/CU), ticket-drained
#define NACC  64                    // accumulator slots (contention spread)

using f32x4 = __attribute__((ext_vector_type(4))) float;

// Software fp32 -> OCP e4m3fn, round-to-nearest-even (r7/r8-verified).
__device__ __forceinline__ unsigned char f2e4m3(float x) {
    unsigned ux = __float_as_uint(x);
    unsigned s  = (ux >> 24) & 0x80u;
    float a = __uint_as_float(ux & 0x7FFFFFFFu);     // |x|, finite for our data
    a = fminf(a, 448.0f);                            // clamp to max finite
    unsigned ua = __float_as_uint(a);
    int eb = (int)(ua >> 23);                        // biased exponent
    if (eb < 121) eb = 121;                          // denormal region: step 2^-9
    float step  = __uint_as_float((unsigned)(eb - 3) << 23);    // 2^(eb-130)
    float istep = __uint_as_float((unsigned)(257 - eb) << 23);  // 2^(130-eb), exact
    float q = rintf(a * istep) * step;               // RNE on e4m3 grid
    q = fminf(q, 448.0f);
    if (q < 0.001953125f)                            // below min denormal 2^-9 -> 0
        return (unsigned char)s;
    unsigned uq = __float_as_uint(q);
    int eq = (int)(uq >> 23) - 127;
    unsigned byte;
    if (eq < -6) byte = (unsigned)(q * 512.0f);      // denormal: d*2^-9, d in 1..7
    else         byte = (unsigned)((eq + 7) << 3) | ((uq >> 20) & 7u);
    return (unsigned char)(s | byte);
}

// Kernel 1 (r2-verified variant, absmax 0): fp32 row norms + fp32->fp8
// conversion into a 16B-granularity swizzled global layout: within each 64B
// k-slab of row r, 16B chunk c is stored at position c ^ ((r>>1)&3).
// The GEMM stage un-swizzles via per-lane SOURCE addressing (rule #21:
// global source is per-lane; LDS dest is lane-linear).
__global__ __launch_bounds__(256) void norm_convert_kernel(
    const float* __restrict__ X, unsigned char* __restrict__ Xq,
    float* __restrict__ norms, float* __restrict__ acc)
{
    const int tid  = threadIdx.x;
    const int lane = tid & 63;
    const int w    = tid >> 6;
    const int row  = blockIdx.x * 4 + w;

    if (blockIdx.x == 0 && tid < NACC + 2) acc[tid] = 0.0f;  // +done +ticket

    const float* xr = X + (size_t)row * DIM + lane * 8;
    float4 v0 = *(const float4*)xr;
    float4 v1 = *(const float4*)(xr + 4);

    float s = 0.0f;
    s = fmaf(v0.x, v0.x, s); s = fmaf(v0.y, v0.y, s);
    s = fmaf(v0.z, v0.z, s); s = fmaf(v0.w, v0.w, s);
    s = fmaf(v1.x, v1.x, s); s = fmaf(v1.y, v1.y, s);
    s = fmaf(v1.z, v1.z, s); s = fmaf(v1.w, v1.w, s);

    union { unsigned char b[8]; uint2 v; } pk;
    pk.b[0] = f2e4m3(v0.x); pk.b[1] = f2e4m3(v0.y);
    pk.b[2] = f2e4m3(v0.z); pk.b[3] = f2e4m3(v0.w);
    pk.b[4] = f2e4m3(v1.x); pk.b[5] = f2e4m3(v1.y);
    pk.b[6] = f2e4m3(v1.z); pk.b[7] = f2e4m3(v1.w);

    const int slab = lane >> 3;                      // 64B slab index (0..7)
    const int c16  = (lane >> 1) & 3;                // 16B chunk in slab
    const int cpos = c16 ^ ((row >> 1) & 3);         // swizzled chunk position
    *(uint2*)(Xq + (size_t)row * DIM + slab * 64 + cpos * 16 + (lane & 1) * 8)
        = pk.v;

    #pragma unroll
    for (int off = 32; off > 0; off >>= 1) s += __shfl_down(s, off, 64);
    if (lane == 0) norms[row] = s;
}

// Async global->LDS DMA, 16B/lane (dest = wave-uniform base + lane*16).
__device__ __forceinline__ void gload16(const void* g, void* l) {
    __builtin_amdgcn_global_load_lds(
        (const __attribute__((address_space(1))) unsigned int*)g,
        (__attribute__((address_space(3))) unsigned int*)l, 16, 0, 0);
}

// Kernel 2 (r8 structural port): persistent ticketed 256x256 upper-tri
// X·X^T with the m201 8-phase RHYTHM (the jointly-required pair m196+m218:
// fine per-phase interleave AND counted vmcnt — every 1-phase schedule this
// session landed at ~35% of MFMA floor):
//   - 8 waves (512 thr), wave = 128x64 output (wm=w>>2, wn=w&3);
//     fp8 16x16x32 MFMA, acc 8x4 f32x4 = 128 VGPR.
//   - K: 16 tiles of BK=32. 3-slot LDS ring (3 x (A 8KB + B 8KB) = 48KB
//     static — r2 proved 66KB static OK; r3's 96KB static = crash suspect).
//   - per K-tile: 2 phases x {frag ds_reads + 1 stage-unit, s_barrier,
//     setprio(1) 16 MFMA setprio(0), s_barrier}. Counted s_waitcnt vmcnt(2)
//     ONCE per tile (end of phase 1), never 0 until the last tile.
//     stage(t+2) -> slot (t+2)%3: its last reader compute(t-1) finished two
//     barriers ago (coarse whole-slot liveness, no fine-grained reuse).
//   - sched_barrier(0) pins around every barrier/wait (rule #18 family).
//   - persistent: NGRID=256 blocks drain 528 tiles via atomic ticket
//     (static 528 blocks at 1/CU would quantize to 3 rounds: +45% tail).
// Staging un-swizzle: lane covers row w*32+(lane>>1), 16B piece jd=lane&1 of
// the 32B k-half; source position = (2*(t&1) + (jd ^ w1)) ^ w3 with
// w1=(lane>>2)&1, w3=(lane>>2)&3 (row bits 1..2 == lane bits 2..3 since row
// bases are multiples of 32). LDS piece jd holds logical chunk jd^w1; frag
// read offset fo = fr*32 + ((q>>1)^((fr>>1)&1))*16 + (q&1)*8 (q=lane>>4).
// NO device-scope fences; fused last-block finalize (r7-verified).
__global__ __launch_bounds__(512, 2) void pair_loss_gemm_kernel(
    const unsigned char* __restrict__ Xq, const float* __restrict__ norms,
    float* __restrict__ acc, float* __restrict__ out)
{
    __shared__ __align__(16) char Ls[3][16384];      // slot = A 8KB | B 8KB
    __shared__ float wsum[8];
    __shared__ int tsh, lastflag;

    const int tid  = threadIdx.x;
    const int lane = tid & 63;
    const int w    = tid >> 6;                       // 0..7
    const int wm   = w >> 2;                         // 0..1 (128-row half)
    const int wn   = w & 3;                          // 0..3 (64-col quarter)

    // frag addressing (constant per thread)
    const int fr = lane & 15;
    const int q  = lane >> 4;
    const int fo = fr * 32 + (((q >> 1) ^ ((fr >> 1) & 1)) * 16) + (q & 1) * 8;

    // staging addressing (constant per thread)
    const int srow = w * 32 + (lane >> 1);           // row within 256-row unit
    const int w3   = (lane >> 2) & 3;
    const int pos0 = ((lane & 1) ^ (w3 & 1)) ^ w3;   // t even: 16B src position
    const int pos1 = pos0 ^ 2;                       // t odd
    const int sdst = w * 1024 + lane * 16;           // lane-linear LDS dest

    unsigned int* ticket = (unsigned int*)acc + NACC + 1;
    float total = 0.0f;

    #pragma unroll 1
    for (;;) {
        __syncthreads();                             // prev ticket quiesce
        if (tid == 0) tsh = (int)atomicAdd(ticket, 1u);
        __syncthreads();
        const int tt = tsh;
        if (tt >= NTRI) break;                       // uniform across block

        // decode tile id -> upper-triangular (bi, bj), bi <= bj
        int u = tt, bi = 0;
        while (u >= (NTB - bi)) { u -= (NTB - bi); bi++; }
        const int bj = bi + u;
        const int rowA = bi * 256;
        const int rowB = bj * 256;

        const unsigned char* gA = Xq + (size_t)(rowA + srow) * DIM;
        const unsigned char* gB = Xq + (size_t)(rowB + srow) * DIM;

        f32x4 accv[8][4];
        const f32x4 zero = {0.0f, 0.0f, 0.0f, 0.0f};
        #pragma unroll
        for (int a = 0; a < 8; a++)
            #pragma unroll
            for (int b = 0; b < 4; b++) accv[a][b] = zero;

        // STG(t_, u_): unit u_=0 -> A k-slice, u_=1 -> B k-slice of tile t_
#define STG(t_, u_) do {                                                   \
        char* d_ = Ls[(t_) % 3] + ((u_) * 8192) + sdst;                    \
        const unsigned char* g_ = ((u_) ? gB : gA) + ((t_) >> 1) * 64      \
                                + (((t_) & 1) ? pos1 : pos0) * 16;         \
        gload16(g_, d_);                                                   \
    } while (0)

        // prologue: tiles 0,1 in flight (depth 2)
        STG(0, 0); STG(0, 1);
        STG(1, 0); STG(1, 1);
        asm volatile("s_waitcnt vmcnt(2)" ::: "memory");   // tile 0 landed
        __builtin_amdgcn_sched_barrier(0);
        __builtin_amdgcn_s_barrier();
        __builtin_amdgcn_sched_barrier(0);

        #pragma unroll 1
        for (int t = 0; t < 16; t++) {
            const char* Ab = Ls[t % 3];
            const char* Bb = Ab + 8192;
            long bf[4];
            #pragma unroll
            for (int p = 0; p < 2; p++) {
                // ---- phase p: frag reads + 1 stage unit ----
                long af[4];
                if (p == 0) {
                    #pragma unroll
                    for (int b = 0; b < 4; b++)
                        bf[b] = *(const long*)(Bb + (wn * 64 + b * 16) * 32 + fo);
                }
                #pragma unroll
                for (int a = 0; a < 4; a++)
                    af[a] = *(const long*)(Ab + (wm * 128 + p * 64 + a * 16) * 32 + fo);
                if (t < 14) STG(t + 2, p);
                __builtin_amdgcn_sched_barrier(0);
                __builtin_amdgcn_s_barrier();
                __builtin_amdgcn_sched_barrier(0);
                // ---- MFMA cluster (16) ----
                __builtin_amdgcn_s_setprio(1);
                #pragma unroll
                for (int a = 0; a < 4; a++)
                    #pragma unroll
                    for (int b = 0; b < 4; b++)
                        accv[p * 4 + a][b] =
                            __builtin_amdgcn_mfma_f32_16x16x32_fp8_fp8(
                                af[a], bf[b], accv[p * 4 + a][b], 0, 0, 0);
                __builtin_amdgcn_s_setprio(0);
                __builtin_amdgcn_sched_barrier(0);
                if (p == 1) {                        // counted wait, once/tile
                    if (t < 14)
                        asm volatile("s_waitcnt vmcnt(2)" ::: "memory");
                    else if (t == 14)
                        asm volatile("s_waitcnt vmcnt(0)" ::: "memory");
                }
                __builtin_amdgcn_sched_barrier(0);
                __builtin_amdgcn_s_barrier();
                __builtin_amdgcn_sched_barrier(0);
            }
        }
#undef STG

        // epilogue: term = exp(-0.1*sqrt(max(ni+nj-2*dot, 0))); diag -> 1
        // C/D: col = lane&15, row = (lane>>4)*4 + reg
        const float wgt = (bi == bj) ? 1.0f : 2.0f;
        float lsum = 0.0f;
        #pragma unroll
        for (int a = 0; a < 8; a++) {
            const int gi0 = rowA + wm * 128 + a * 16 + (lane >> 4) * 4;
            #pragma unroll
            for (int b = 0; b < 4; b++) {
                const int gj = rowB + wn * 64 + b * 16 + (lane & 15);
                const float nj = norms[gj];
                #pragma unroll
                for (int r = 0; r < 4; r++) {
                    const int gi = gi0 + r;
                    float sq = fmaf(-2.0f, accv[a][b][r], norms[gi] + nj);
                    sq = fmaxf(sq, 0.0f);
                    float term = __expf(-0.1f * sqrtf(sq));
                    if (gi == gj) term = 1.0f;
                    lsum += term;
                }
            }
        }
        total += wgt * lsum;
    }

    // per-block reduction over all tickets, one atomic per block
    #pragma unroll
    for (int off = 32; off > 0; off >>= 1) total += __shfl_down(total, off, 64);
    if (lane == 0) wsum[w] = total;
    __syncthreads();

    // fused finalize (r7-verified): last block sums the NACC slots.
    // Ordering WITHOUT a device fence: done-counter atomic issued only after
    // this block's acc-RMW returned (asm keeps value live; in-order issue).
    if (tid == 0) {
        float bsum = 0.0f;
        #pragma unroll
        for (int i = 0; i < 8; i++) bsum += wsum[i];
        float old = atomicAdd(&acc[blockIdx.x & (NACC - 1)], bsum);
        asm volatile("" :: "v"(old));
        unsigned prev = atomicAdd((unsigned int*)(acc + NACC), 1u);
        lastflag = (prev == NGRID - 1) ? 1 : 0;
    }
    __syncthreads();
    if (lastflag && tid < 64) {
        float v = atomicAdd(&acc[tid], 0.0f);    // coherent read (device atomic)
        #pragma unroll
        for (int off = 32; off > 0; off >>= 1) v += __shfl_down(v, off, 64);
        if (tid == 0) {
            const float inv = 1.0f / ((float)NROWS * (float)NROWS); // 2^-26
            float loss = v * inv * 0.1f;
            out[0] = loss;
            out[1] = 0.5f * loss;
        }
    }
}

extern "C" void kernel_launch(void* const* d_in, const int* in_sizes, int n_in,
                              void* d_out, int out_size, void* d_ws, size_t ws_size,
                              hipStream_t stream)
{
    const float* X = (const float*)d_in[0];
    float* out = (float*)d_out;

    char* ws = (char*)d_ws;
    float*         acc   = (float*)ws;                   // NACC + done + ticket
    float*         norms = (float*)(ws + 1024);          // 8192 fp32 (32 KB)
    unsigned char* Xq    = (unsigned char*)(ws + 1024 + 32768); // fp8 X, 4 MB

    norm_convert_kernel<<<NROWS / 4, 256, 0, stream>>>(X, Xq, norms, acc);
    pair_loss_gemm_kernel<<<NGRID, 512, 0, stream>>>(Xq, norms, acc, out);
}

// Round 9
// 107.768 us; speedup vs baseline: 1.3945x; 1.3945x over previous
//
#include <hip/hip_runtime.h>

// Problem constants
#define NROWS 8192   // 4 * 2048
#define DIM   512
#define NT    64                    // 8192 / 128 tiles per side
#define NTRI  (NT * (NT + 1) / 2)   // 2080 upper-triangular tile blocks
#define NACC  64                    // accumulator slots (contention spread)

using f32x4 = __attribute__((ext_vector_type(4))) float;

// Software fp32 -> OCP e4m3fn, round-to-nearest-even (r7/r8-verified).
__device__ __forceinline__ unsigned char f2e4m3(float x) {
    unsigned ux = __float_as_uint(x);
    unsigned s  = (ux >> 24) & 0x80u;
    float a = __uint_as_float(ux & 0x7FFFFFFFu);     // |x|, finite for our data
    a = fminf(a, 448.0f);                            // clamp to max finite
    unsigned ua = __float_as_uint(a);
    int eb = (int)(ua >> 23);                        // biased exponent
    if (eb < 121) eb = 121;                          // denormal region: step 2^-9
    float step  = __uint_as_float((unsigned)(eb - 3) << 23);    // 2^(eb-130)
    float istep = __uint_as_float((unsigned)(257 - eb) << 23);  // 2^(130-eb), exact
    float q = rintf(a * istep) * step;               // RNE on e4m3 grid
    q = fminf(q, 448.0f);
    if (q < 0.001953125f)                            // below min denormal 2^-9 -> 0
        return (unsigned char)s;
    unsigned uq = __float_as_uint(q);
    int eq = (int)(uq >> 23) - 127;
    unsigned byte;
    if (eq < -6) byte = (unsigned)(q * 512.0f);      // denormal: d*2^-9, d in 1..7
    else         byte = (unsigned)((eq + 7) << 3) | ((uq >> 20) & 7u);
    return (unsigned char)(s | byte);
}

// Kernel 1 (r0-exact, champion config): fp32 row norms + fp32->fp8 convert
// into the pre-swizzled global layout for BK=64 tiles: within each 64B
// k-slab of row r, 8B chunk c stored at position c ^ (r&7). GEMM staging
// stays a straight linear copy; frag reads <=2-way in LDS (free, m136).
__global__ __launch_bounds__(256) void norm_convert_kernel(
    const float* __restrict__ X, unsigned char* __restrict__ Xq,
    float* __restrict__ norms, float* __restrict__ acc)
{
    const int tid  = threadIdx.x;
    const int lane = tid & 63;
    const int w    = tid >> 6;
    const int row  = blockIdx.x * 4 + w;

    if (blockIdx.x == 0 && tid < NACC) acc[tid] = 0.0f;

    const float* xr = X + (size_t)row * DIM + lane * 8;
    float4 v0 = *(const float4*)xr;
    float4 v1 = *(const float4*)(xr + 4);

    float s = 0.0f;
    s = fmaf(v0.x, v0.x, s); s = fmaf(v0.y, v0.y, s);
    s = fmaf(v0.z, v0.z, s); s = fmaf(v0.w, v0.w, s);
    s = fmaf(v1.x, v1.x, s); s = fmaf(v1.y, v1.y, s);
    s = fmaf(v1.z, v1.z, s); s = fmaf(v1.w, v1.w, s);

    union { unsigned char b[8]; uint2 v; } pk;
    pk.b[0] = f2e4m3(v0.x); pk.b[1] = f2e4m3(v0.y);
    pk.b[2] = f2e4m3(v0.z); pk.b[3] = f2e4m3(v0.w);
    pk.b[4] = f2e4m3(v1.x); pk.b[5] = f2e4m3(v1.y);
    pk.b[6] = f2e4m3(v1.z); pk.b[7] = f2e4m3(v1.w);

    const int slab = lane >> 3;                      // 64B slab index (0..7)
    const int cpos = (lane & 7) ^ (row & 7);         // swizzled 8B position
    *(uint2*)(Xq + (size_t)row * DIM + slab * 64 + cpos * 8) = pk.v;

    #pragma unroll
    for (int off = 32; off > 0; off >>= 1) s += __shfl_down(s, off, 64);
    if (lane == 0) norms[row] = s;
}

// Epilogue specialized on the uniform (bi==bj) branch: off-diag blocks
// (97% of 2080) carry ZERO per-term compare/cndmask. ni via float4 (gi0 is
// 4-aligned), nj hoisted: 64 scalar norm loads -> 8 vector/scalar loads.
// exp(-0.1*sqrt(sq)) == exp2(C*sqrt(sq)), C = -0.1*log2(e): one mul saved
// per term (v_sqrt + v_mul + v_exp, all native).
template <bool DIAG>
__device__ __forceinline__ float tile_epilogue(
    const f32x4 (&accv)[4][4], const float* __restrict__ norms,
    int rowA, int rowB, int wr, int wc, int lane)
{
    const int q4 = (lane >> 4) * 4;
    const int fr = lane & 15;
    const float C = -0.14426950408889634f;           // -0.1 * log2(e)
    float njv[4];
    #pragma unroll
    for (int b = 0; b < 4; b++) njv[b] = norms[rowB + wc + b * 16 + fr];
    float lsum = 0.0f;
    #pragma unroll
    for (int a = 0; a < 4; a++) {
        const int gi0 = rowA + wr + a * 16 + q4;
        const float4 niv = *(const float4*)(norms + gi0);
        const float ni[4] = {niv.x, niv.y, niv.z, niv.w};
        #pragma unroll
        for (int b = 0; b < 4; b++) {
            const int gj = rowB + wc + b * 16 + fr;
            #pragma unroll
            for (int r = 0; r < 4; r++) {
                float sq = fmaf(-2.0f, accv[a][b][r], ni[r] + njv[b]);
                sq = fmaxf(sq, 0.0f);
                float term = exp2f(C * sqrtf(sq));
                if (DIAG) { if (gi0 + r == gj) term = 1.0f; }
                lsum += term;
            }
        }
    }
    return lsum;
}

// Kernel 2: upper-triangular tiled X·X^T (fp8 e4m3 MFMA) + fused epilogue.
// Body = r0 champion UNCHANGED (structural ledger after 8 rounds: 2-barrier
// 128x128 / 4-wave / BK=64 / reg-staged dbuf / 4 blocks-per-CU beats gload_lds
// (48.8), MX BK=64 (48.8) / BK=128 (58.2), counted-vmcnt ring (50.1),
// register-direct (85), 8-phase (91.7) — TLP at 4 blocks/CU is what hides
// the barrier drains at this problem's small K).
// r9 deltas ONLY: (1) XCD-chunked bid remap (2080 = 8*260, bijective;
// A-panel L2 locality, zero correctness risk); (2) epilogue VALU cuts
// (VALUBusy 62.6% was the closest-to-saturated pipe; see tile_epilogue).
// NO device-scope fences; NO cooperative launch (r6: silent failure).
__global__ __launch_bounds__(256, 4) void pair_loss_gemm_kernel(
    const unsigned char* __restrict__ Xq, const float* __restrict__ norms,
    float* __restrict__ acc)
{
    __shared__ __align__(16) char As0[8192];
    __shared__ __align__(16) char As1[8192];
    __shared__ __align__(16) char Bs0[8192];
    __shared__ __align__(16) char Bs1[8192];
    __shared__ float wsum[4];

    // XCD-chunked remap, then decode -> upper-triangular (bi, bj), bi <= bj
    const int bid = (blockIdx.x & 7) * 260 + (blockIdx.x >> 3);
    int t = bid, bi = 0;
    while (t >= (NT - bi)) { t -= (NT - bi); bi++; }
    const int bj = bi + t;

    const int tid  = threadIdx.x;
    const int lane = tid & 63;
    const int w    = tid >> 6;

    const int rowA = bi * 128;
    const int rowB = bj * 128;

    f32x4 accv[4][4];
    const f32x4 zero = {0.0f, 0.0f, 0.0f, 0.0f};
    #pragma unroll
    for (int a = 0; a < 4; a++)
        #pragma unroll
        for (int b = 0; b < 4; b++) accv[a][b] = zero;

    // staging: thread -> row r0 = tid>>1, 32B half h0 = tid&1 of the 64B slab.
    const int r0 = tid >> 1;
    const int h0 = tid & 1;
    const int wb = r0 * 64 + h0 * 32;            // LDS byte offset
    const unsigned char* gA = Xq + (size_t)(rowA + r0) * DIM + h0 * 32;
    const unsigned char* gB = Xq + (size_t)(rowB + r0) * DIM + h0 * 32;

    // MFMA fp8 frag: lane holds A[m=fr][k=q*8..q*8+7] per k-step, q=lane>>4.
    // Chunk index in the 64B slab: kstep*4+q, at swizzled position ^(fr&7).
    const int fr  = lane & 15;
    const int q   = lane >> 4;
    const int fo0 = fr * 64 + ((q ^ (fr & 7)) * 8);
    const int wr  = (w & 1) * 64;
    const int wc  = (w >> 1) * 64;

    // prologue: stage slab 0 through registers
    {
        uint4 pa0 = *(const uint4*)gA;
        uint4 pa1 = *(const uint4*)(gA + 16);
        uint4 pb0 = *(const uint4*)gB;
        uint4 pb1 = *(const uint4*)(gB + 16);
        *(uint4*)(As0 + wb)      = pa0;
        *(uint4*)(As0 + wb + 16) = pa1;
        *(uint4*)(Bs0 + wb)      = pb0;
        *(uint4*)(Bs0 + wb + 16) = pb1;
    }
    __syncthreads();

    char* curA = As0; char* nxtA = As1;
    char* curB = Bs0; char* nxtB = Bs1;

    #pragma unroll 1
    for (int k = 0; k < 8; k++) {
        // prefetch next 64B K-slab into registers (in flight across 2 k-steps)
        uint4 pa0, pa1, pb0, pb1;
        const bool more = (k < 7);
        if (more) {
            const int k0 = (k + 1) * 64;
            pa0 = *(const uint4*)(gA + k0);
            pa1 = *(const uint4*)(gA + k0 + 16);
            pb0 = *(const uint4*)(gB + k0);
            pb1 = *(const uint4*)(gB + k0 + 16);
        }

        #pragma unroll
        for (int s = 0; s < 2; s++) {
            const int fo = fo0 ^ (s << 5);
            long af[4], bf[4];
            #pragma unroll
            for (int a = 0; a < 4; a++)
                af[a] = *(const long*)(curA + (wr + a * 16) * 64 + fo);
            #pragma unroll
            for (int b = 0; b < 4; b++)
                bf[b] = *(const long*)(curB + (wc + b * 16) * 64 + fo);
            #pragma unroll
            for (int a = 0; a < 4; a++)
                #pragma unroll
                for (int b = 0; b < 4; b++)
                    accv[a][b] = __builtin_amdgcn_mfma_f32_16x16x32_fp8_fp8(
                        af[a], bf[b], accv[a][b], 0, 0, 0);
        }

        if (more) {
            *(uint4*)(nxtA + wb)      = pa0;  // vmcnt wait lands here
            *(uint4*)(nxtA + wb + 16) = pa1;
            *(uint4*)(nxtB + wb)      = pb0;
            *(uint4*)(nxtB + wb + 16) = pb1;
            __syncthreads();
            char* tA = curA; curA = nxtA; nxtA = tA;
            char* tB = curB; curB = nxtB; nxtB = tB;
        }
    }

    // epilogue (uniform branch: bi==bj is block-constant)
    float lsum = (bi == bj)
        ? tile_epilogue<true >(accv, norms, rowA, rowB, wr, wc, lane)
        : 2.0f * tile_epilogue<false>(accv, norms, rowA, rowB, wr, wc, lane);

    #pragma unroll
    for (int off = 32; off > 0; off >>= 1) lsum += __shfl_down(lsum, off, 64);
    if (lane == 0) wsum[w] = lsum;
    __syncthreads();
    if (tid == 0)
        atomicAdd(&acc[bid & (NACC - 1)],
                  wsum[0] + wsum[1] + wsum[2] + wsum[3]);
}

// Kernel 3 (r0-exact): finalize scalar outputs (sum NACC slots)
__global__ void finalize_kernel(const float* __restrict__ acc,
                                float* __restrict__ out)
{
    const int lane = threadIdx.x;
    float s = (lane < NACC) ? acc[lane] : 0.0f;
    #pragma unroll
    for (int off = 32; off > 0; off >>= 1) s += __shfl_down(s, off, 64);
    if (lane == 0) {
        const float inv = 1.0f / ((float)NROWS * (float)NROWS); // 2^-26 exact
        float loss = s * inv * 0.1f;
        out[0] = loss;
        out[1] = 0.5f * loss;
    }
}

extern "C" void kernel_launch(void* const* d_in, const int* in_sizes, int n_in,
                              void* d_out, int out_size, void* d_ws, size_t ws_size,
                              hipStream_t stream)
{
    const float* X = (const float*)d_in[0];
    float* out = (float*)d_out;

    char* ws = (char*)d_ws;
    float*         acc   = (float*)ws;                   // NACC fp32 slots
    float*         norms = (float*)(ws + 1024);          // 8192 fp32 (32 KB)
    unsigned char* Xq    = (unsigned char*)(ws + 1024 + 32768); // fp8 X, 4 MB

    norm_convert_kernel<<<NROWS / 4, 256, 0, stream>>>(X, Xq, norms, acc);
    pair_loss_gemm_kernel<<<NTRI, 256, 0, stream>>>(Xq, norms, acc);
    finalize_kernel<<<1, 64, 0, stream>>>(acc, out);
}